// Round 1
// baseline (3455.848 us; speedup 1.0000x reference)
//
#include <hip/hip_runtime.h>

// Problem constants (from reference)
// B=16384, motions width=256, LAT=32, IN=288, H1=H2=512, MOE=8, OUT=128

__device__ __forceinline__ float elu_f(float x) { return x > 0.f ? x : (__expf(x) - 1.f); }

__device__ __forceinline__ void fma8(float& a0, float& a1, float4 xv, const float2* w) {
    a0 += xv.x * w[0].x; a1 += xv.x * w[0].y;
    a0 += xv.y * w[1].x; a1 += xv.y * w[1].y;
    a0 += xv.z * w[2].x; a1 += xv.z * w[2].y;
    a0 += xv.w * w[3].x; a1 += xv.w * w[3].y;
}

// ---------------- gate MLP: para = elu(elu(elu(x@gw1+gb1)@gw2+gb2)@gw3+gb3) ----------------
// 16 rows per block, 256 threads. LDS: hA = h1, hB = x-tile (stride 288) then h2 (stride 512).
__global__ __launch_bounds__(256, 2) void gate_kernel(
    const float* __restrict__ motions, const float* __restrict__ z,
    const float* __restrict__ gw1, const float* __restrict__ gb1,
    const float* __restrict__ gw2, const float* __restrict__ gb2,
    const float* __restrict__ gw3, const float* __restrict__ gb3,
    float* __restrict__ para, float* __restrict__ partial)
{
    __shared__ float hA[16 * 512];
    __shared__ float hB[16 * 512];
    __shared__ float red[128];
    const int t = threadIdx.x;
    const int r0 = blockIdx.x * 16;

    // stage x = [motions | z] rows into hB, stride 288
    for (int i = t; i < 16 * 64; i += 256) {               // motions: 16*256 floats as float4
        int r = i >> 6, c = i & 63;
        *(float4*)&hB[r * 288 + c * 4] = ((const float4*)motions)[(r0 + r) * 64 + c];
    }
    for (int i = t; i < 16 * 8; i += 256) {                // z: 16*32 floats as float4
        int r = i >> 3, c = i & 7;
        *(float4*)&hB[r * 288 + 256 + c * 4] = ((const float4*)z)[(r0 + r) * 8 + c];
    }
    __syncthreads();

    // ---- layer 1: x(288) @ gw1 -> hA ----
    {
        const int o = 2 * t;
        float a0[16], a1[16];
        #pragma unroll
        for (int r = 0; r < 16; ++r) { a0[r] = 0.f; a1[r] = 0.f; }
        const float* Wp = gw1 + o;
        float2 w[4], wn[4];
        #pragma unroll
        for (int kk = 0; kk < 4; ++kk) w[kk] = *(const float2*)(Wp + kk * 512);
        for (int k = 0; k < 288; k += 4) {
            if (k + 4 < 288) {
                #pragma unroll
                for (int kk = 0; kk < 4; ++kk) wn[kk] = *(const float2*)(Wp + (k + 4 + kk) * 512);
            }
            #pragma unroll
            for (int r = 0; r < 16; ++r)
                fma8(a0[r], a1[r], *(const float4*)&hB[r * 288 + k], w);
            #pragma unroll
            for (int kk = 0; kk < 4; ++kk) w[kk] = wn[kk];
        }
        const float bb0 = gb1[o], bb1 = gb1[o + 1];
        #pragma unroll
        for (int r = 0; r < 16; ++r)
            *(float2*)&hA[r * 512 + o] = make_float2(elu_f(a0[r] + bb0), elu_f(a1[r] + bb1));
    }
    __syncthreads();

    // ---- layer 2: h1(512) @ gw2 -> hB (stride 512) ----
    {
        const int o = 2 * t;
        float a0[16], a1[16];
        #pragma unroll
        for (int r = 0; r < 16; ++r) { a0[r] = 0.f; a1[r] = 0.f; }
        const float* Wp = gw2 + o;
        float2 w[4], wn[4];
        #pragma unroll
        for (int kk = 0; kk < 4; ++kk) w[kk] = *(const float2*)(Wp + kk * 512);
        for (int k = 0; k < 512; k += 4) {
            if (k + 4 < 512) {
                #pragma unroll
                for (int kk = 0; kk < 4; ++kk) wn[kk] = *(const float2*)(Wp + (k + 4 + kk) * 512);
            }
            #pragma unroll
            for (int r = 0; r < 16; ++r)
                fma8(a0[r], a1[r], *(const float4*)&hA[r * 512 + k], w);
            #pragma unroll
            for (int kk = 0; kk < 4; ++kk) w[kk] = wn[kk];
        }
        const float bb0 = gb2[o], bb1 = gb2[o + 1];
        __syncthreads();   // all layer-1 x reads of hB are done (loop above finished for all threads)
        #pragma unroll
        for (int r = 0; r < 16; ++r)
            *(float2*)&hB[r * 512 + o] = make_float2(elu_f(a0[r] + bb0), elu_f(a1[r] + bb1));
    }
    __syncthreads();

    // ---- layer 3: h2(512) @ gw3 -> para [16][8] ----
    float pv = 0.f;
    if (t < 128) {
        const int r = t >> 3, e = t & 7;
        float acc = 0.f;
        for (int k = 0; k < 512; k += 4) {
            float4 hv = *(const float4*)&hB[r * 512 + k];
            acc += hv.x * gw3[k * 8 + e];
            acc += hv.y * gw3[(k + 1) * 8 + e];
            acc += hv.z * gw3[(k + 2) * 8 + e];
            acc += hv.w * gw3[(k + 3) * 8 + e];
        }
        float p = elu_f(acc + gb3[e]);
        para[(r0 + r) * 8 + e] = p;
        pv = p * p;
        red[t] = pv;
    }
    __syncthreads();
    for (int s = 64; s >= 1; s >>= 1) {
        if (t < s) red[t] += red[t + s];
        __syncthreads();
    }
    if (t == 0) partial[blockIdx.x] = red[0];
}

// ---------------- deterministic norm finalize: inv_norm = 1/sqrt(sum partial) ----------------
__global__ void finalize_kernel(const float* __restrict__ partial, float* __restrict__ invn)
{
    __shared__ float red[256];
    const int t = threadIdx.x;
    red[t] = partial[t] + partial[t + 256] + partial[t + 512] + partial[t + 768];
    __syncthreads();
    for (int s = 128; s >= 1; s >>= 1) {
        if (t < s) red[t] += red[t + s];
        __syncthreads();
    }
    if (t == 0) invn[0] = 1.0f / sqrtf(red[0]);
}

// ---------------- experts: all 8 experts fused per 32-row tile ----------------
__global__ __launch_bounds__(256, 1) void expert_kernel(
    const float* __restrict__ motions, const float* __restrict__ z,
    const float* __restrict__ W1, const float* __restrict__ b1,
    const float* __restrict__ W2, const float* __restrict__ b2,
    const float* __restrict__ W3, const float* __restrict__ b3,
    const float* __restrict__ para, const float* __restrict__ invn,
    float* __restrict__ out)
{
    __shared__ float h1s[32 * 512];   // 64 KB
    __shared__ float bufB[32 * 512];  // 64 KB: x tile (stride 256) / h2 (stride 512)
    __shared__ float zt[32 * 32];     // 4 KB
    __shared__ float ps[32 * 8];      // 1 KB
    const int t = threadIdx.x;
    const int r0 = blockIdx.x * 32;
    const int o2 = 2 * t;
    const int o3 = t & 127;
    const int rb3 = (t >> 7) * 16;

    ((float4*)zt)[t] = ((const float4*)z)[r0 * 8 + t];   // 32*32 floats = 256 float4
    ps[t] = para[r0 * 8 + t];                            // 32*8 = 256 floats
    const float inv_norm = invn[0];

    float oacc[16];
    #pragma unroll
    for (int r = 0; r < 16; ++r) oacc[r] = 0.f;

    for (int e = 0; e < 8; ++e) {
        __syncthreads();   // previous expert's h2 reads (and zt/ps init) complete
        // re-stage motions rows into bufB (stride 256); cheap, L2-resident
        #pragma unroll
        for (int i = 0; i < 8; ++i)
            ((float4*)bufB)[t + i * 256] = ((const float4*)motions)[r0 * 64 + t + i * 256];
        __syncthreads();

        const float* W1e = W1 + e * 288 * 512;
        const float* W2e = W2 + e * 544 * 512;
        const float* W3e = W3 + e * 544 * 128;

        // ---- layer 1: [x|z](288) @ W1e -> h1s ----
        {
            float a0[32], a1[32];
            #pragma unroll
            for (int r = 0; r < 32; ++r) { a0[r] = 0.f; a1[r] = 0.f; }
            const float* Wp = W1e + o2;
            float2 w[4], wn[4];
            #pragma unroll
            for (int kk = 0; kk < 4; ++kk) w[kk] = *(const float2*)(Wp + kk * 512);
            for (int k = 0; k < 256; k += 4) {
                #pragma unroll
                for (int kk = 0; kk < 4; ++kk) wn[kk] = *(const float2*)(Wp + (k + 4 + kk) * 512);
                #pragma unroll
                for (int r = 0; r < 32; ++r)
                    fma8(a0[r], a1[r], *(const float4*)&bufB[r * 256 + k], w);
                #pragma unroll
                for (int kk = 0; kk < 4; ++kk) w[kk] = wn[kk];
            }
            for (int k = 256; k < 288; k += 4) {
                if (k + 4 < 288) {
                    #pragma unroll
                    for (int kk = 0; kk < 4; ++kk) wn[kk] = *(const float2*)(Wp + (k + 4 + kk) * 512);
                }
                #pragma unroll
                for (int r = 0; r < 32; ++r)
                    fma8(a0[r], a1[r], *(const float4*)&zt[r * 32 + (k - 256)], w);
                #pragma unroll
                for (int kk = 0; kk < 4; ++kk) w[kk] = wn[kk];
            }
            const float bb0 = b1[e * 512 + o2], bb1 = b1[e * 512 + o2 + 1];
            #pragma unroll
            for (int r = 0; r < 32; ++r)
                *(float2*)&h1s[r * 512 + o2] = make_float2(elu_f(a0[r] + bb0), elu_f(a1[r] + bb1));
        }
        __syncthreads();

        // ---- layer 2: [h1|z](544) @ W2e -> bufB (h2, stride 512) ----
        {
            float a0[32], a1[32];
            #pragma unroll
            for (int r = 0; r < 32; ++r) { a0[r] = 0.f; a1[r] = 0.f; }
            const float* Wp = W2e + o2;
            float2 w[4], wn[4];
            #pragma unroll
            for (int kk = 0; kk < 4; ++kk) w[kk] = *(const float2*)(Wp + kk * 512);
            for (int k = 0; k < 512; k += 4) {
                #pragma unroll
                for (int kk = 0; kk < 4; ++kk) wn[kk] = *(const float2*)(Wp + (k + 4 + kk) * 512);
                #pragma unroll
                for (int r = 0; r < 32; ++r)
                    fma8(a0[r], a1[r], *(const float4*)&h1s[r * 512 + k], w);
                #pragma unroll
                for (int kk = 0; kk < 4; ++kk) w[kk] = wn[kk];
            }
            for (int k = 512; k < 544; k += 4) {
                if (k + 4 < 544) {
                    #pragma unroll
                    for (int kk = 0; kk < 4; ++kk) wn[kk] = *(const float2*)(Wp + (k + 4 + kk) * 512);
                }
                #pragma unroll
                for (int r = 0; r < 32; ++r)
                    fma8(a0[r], a1[r], *(const float4*)&zt[r * 32 + (k - 512)], w);
                #pragma unroll
                for (int kk = 0; kk < 4; ++kk) w[kk] = wn[kk];
            }
            const float bb0 = b2[e * 512 + o2], bb1 = b2[e * 512 + o2 + 1];
            #pragma unroll
            for (int r = 0; r < 32; ++r)
                *(float2*)&bufB[r * 512 + o2] = make_float2(elu_f(a0[r] + bb0), elu_f(a1[r] + bb1));
        }
        __syncthreads();

        // ---- layer 3: [h2|z](544) @ W3e, gated accumulate ----
        {
            float a[16];
            #pragma unroll
            for (int r = 0; r < 16; ++r) a[r] = 0.f;
            const float* Wp = W3e + o3;
            float w0 = Wp[0], w1 = Wp[128], w2 = Wp[256], w3 = Wp[384];
            for (int k = 0; k < 512; k += 4) {
                float n0 = Wp[(k + 4) * 128], n1 = Wp[(k + 5) * 128];
                float n2 = Wp[(k + 6) * 128], n3 = Wp[(k + 7) * 128];
                #pragma unroll
                for (int r = 0; r < 16; ++r) {
                    float4 hv = *(const float4*)&bufB[(rb3 + r) * 512 + k];
                    a[r] += hv.x * w0 + hv.y * w1 + hv.z * w2 + hv.w * w3;
                }
                w0 = n0; w1 = n1; w2 = n2; w3 = n3;
            }
            for (int k = 512; k < 544; k += 4) {
                float n0 = 0.f, n1 = 0.f, n2 = 0.f, n3 = 0.f;
                if (k + 4 < 544) {
                    n0 = Wp[(k + 4) * 128]; n1 = Wp[(k + 5) * 128];
                    n2 = Wp[(k + 6) * 128]; n3 = Wp[(k + 7) * 128];
                }
                #pragma unroll
                for (int r = 0; r < 16; ++r) {
                    float4 hv = *(const float4*)&zt[(rb3 + r) * 32 + (k - 512)];
                    a[r] += hv.x * w0 + hv.y * w1 + hv.z * w2 + hv.w * w3;
                }
                w0 = n0; w1 = n1; w2 = n2; w3 = n3;
            }
            const float bb = b3[e * 128 + o3];
            #pragma unroll
            for (int r = 0; r < 16; ++r) {
                float h3 = elu_f(a[r] + bb);
                oacc[r] += ps[(rb3 + r) * 8 + e] * h3;
            }
        }
    }

    #pragma unroll
    for (int r = 0; r < 16; ++r) {
        float v = oacc[r] * inv_norm;
        out[(r0 + rb3 + r) * 128 + o3] = 1.0f / (1.0f + __expf(-v));
    }
}

extern "C" void kernel_launch(void* const* d_in, const int* in_sizes, int n_in,
                              void* d_out, int out_size, void* d_ws, size_t ws_size,
                              hipStream_t stream) {
    const float* motions = (const float*)d_in[0];
    const float* z   = (const float*)d_in[1];
    const float* gw1 = (const float*)d_in[2];
    const float* gb1 = (const float*)d_in[3];
    const float* gw2 = (const float*)d_in[4];
    const float* gb2 = (const float*)d_in[5];
    const float* gw3 = (const float*)d_in[6];
    const float* gb3 = (const float*)d_in[7];
    const float* W1  = (const float*)d_in[8];
    const float* b1  = (const float*)d_in[9];
    const float* W2  = (const float*)d_in[10];
    const float* b2  = (const float*)d_in[11];
    const float* W3  = (const float*)d_in[12];
    const float* b3  = (const float*)d_in[13];
    float* wsf = (float*)d_ws;
    float* invn    = wsf;          // [0]
    float* partial = wsf + 16;     // [16 .. 16+1024)
    float* para    = wsf + 2048;   // [2048 .. 2048+16384*8)
    float* out = (float*)d_out;

    gate_kernel<<<dim3(1024), dim3(256), 0, stream>>>(motions, z, gw1, gb1, gw2, gb2, gw3, gb3,
                                                      para, partial);
    finalize_kernel<<<dim3(1), dim3(256), 0, stream>>>(partial, invn);
    expert_kernel<<<dim3(512), dim3(256), 0, stream>>>(motions, z, W1, b1, W2, b2, W3, b3,
                                                       para, invn, out);
}

// Round 2
// 308.352 us; speedup vs baseline: 11.2075x; 11.2075x over previous
//
#include <hip/hip_runtime.h>

// B=16384, motions width=256, LAT=32, IN=288, H1=H2=512, MOE=8, OUT=128
// All GEMMs via v_mfma_f32_16x16x32_bf16. Weights transposed to [N][K] bf16 in ws.

typedef __attribute__((ext_vector_type(8))) short bf16x8;
typedef __attribute__((ext_vector_type(4))) float f32x4;
#define MFMA(a, b, c) __builtin_amdgcn_mfma_f32_16x16x32_bf16(a, b, c, 0, 0, 0)

#define STRIDE 552   // LDS row stride in bf16: 552*2B=1104B=276dw, 276%32=20 -> conflict-free frag reads

__device__ __forceinline__ float elu_f(float x) { return x > 0.f ? x : (__expf(x) - 1.f); }

__device__ __forceinline__ ushort f2bf(float f) {
    union { float f; unsigned u; } v; v.f = f;
    unsigned r = v.u + 0x7fffu + ((v.u >> 16) & 1u);   // RNE
    return (ushort)(r >> 16);
}
__device__ __forceinline__ float bf2f(ushort u) {
    union { unsigned u; float f; } v; v.u = ((unsigned)u) << 16;
    return v.f;
}

// ---------------- prep: xz = concat(motions, z) as bf16 [16384][288] ----------------
__global__ void prep_xz(const float* __restrict__ motions, const float* __restrict__ z,
                        ushort* __restrict__ xz) {
    int i = blockIdx.x * 256 + threadIdx.x;      // over 16384*72 float4 chunks
    int r = i / 72, c = i % 72;
    float4 v = (c < 64) ? ((const float4*)motions)[r * 64 + c]
                        : ((const float4*)z)[r * 8 + (c - 64)];
    ushort4 o;
    o.x = f2bf(v.x); o.y = f2bf(v.y); o.z = f2bf(v.z); o.w = f2bf(v.w);
    *(ushort4*)(xz + (size_t)r * 288 + c * 4) = o;
}

// ---------------- prep: transpose+convert  in[E][K][N] f32 -> out[E][N][K] bf16 ----------------
__global__ void prep_transpose(const float* __restrict__ in, ushort* __restrict__ out,
                               int K, int N) {
    __shared__ float tile[32][33];
    const int e = blockIdx.z;
    const float* inp = in + (size_t)e * K * N;
    ushort* outp = out + (size_t)e * N * K;
    const int k0 = blockIdx.x * 32, n0 = blockIdx.y * 32;
    const int tx = threadIdx.x, ty = threadIdx.y;  // 32 x 8
    #pragma unroll
    for (int i = 0; i < 4; ++i)
        tile[ty + i * 8][tx] = inp[(size_t)(k0 + ty + i * 8) * N + n0 + tx];
    __syncthreads();
    #pragma unroll
    for (int i = 0; i < 4; ++i)
        outp[(size_t)(n0 + ty + i * 8) * K + k0 + tx] = f2bf(tile[tx][ty + i * 8]);
}

// ---------------- gate MLP (MFMA layers 1-2, scalar layer 3) ----------------
__global__ __launch_bounds__(512, 2) void gate_kernel(
    const ushort* __restrict__ xz,
    const ushort* __restrict__ gw1t, const float* __restrict__ gb1,
    const ushort* __restrict__ gw2t, const float* __restrict__ gb2,
    const float* __restrict__ gw3, const float* __restrict__ gb3,
    float* __restrict__ para, float* __restrict__ partial)
{
    __shared__ ushort hA[64 * STRIDE];
    __shared__ ushort hB[64 * STRIDE];
    __shared__ float red[512];
    const int t = threadIdx.x;
    const int lane = t & 63, w = t >> 6;
    const int lr = lane & 15, lk = lane >> 4;
    const int r0 = blockIdx.x * 64;

    for (int i = t; i < 64 * 36; i += 512) {
        int r = i / 36, c = i % 36;
        *(uint4*)&hB[r * STRIDE + c * 8] = *(const uint4*)(xz + (size_t)(r0 + r) * 288 + c * 8);
    }
    __syncthreads();

    // L1: [64,288] @ gw1t^T -> hA [64,512]
    {
        f32x4 acc[4][4] = {};
        const int n0 = w * 64;
        for (int ks = 0; ks < 9; ++ks) {
            bf16x8 a[4], b[4];
            #pragma unroll
            for (int mf = 0; mf < 4; ++mf)
                a[mf] = *(const bf16x8*)&hB[(mf * 16 + lr) * STRIDE + ks * 32 + lk * 8];
            #pragma unroll
            for (int nf = 0; nf < 4; ++nf)
                b[nf] = *(const bf16x8*)(gw1t + (size_t)(n0 + nf * 16 + lr) * 288 + ks * 32 + lk * 8);
            #pragma unroll
            for (int mf = 0; mf < 4; ++mf)
                #pragma unroll
                for (int nf = 0; nf < 4; ++nf)
                    acc[mf][nf] = MFMA(a[mf], b[nf], acc[mf][nf]);
        }
        #pragma unroll
        for (int nf = 0; nf < 4; ++nf) {
            int col = n0 + nf * 16 + lr;
            float bb = gb1[col];
            #pragma unroll
            for (int mf = 0; mf < 4; ++mf)
                #pragma unroll
                for (int j = 0; j < 4; ++j)
                    hA[(mf * 16 + lk * 4 + j) * STRIDE + col] = f2bf(elu_f(acc[mf][nf][j] + bb));
        }
    }
    __syncthreads();

    // L2: [64,512] @ gw2t^T -> hB [64,512]
    {
        f32x4 acc[4][4] = {};
        const int n0 = w * 64;
        for (int ks = 0; ks < 16; ++ks) {
            bf16x8 a[4], b[4];
            #pragma unroll
            for (int mf = 0; mf < 4; ++mf)
                a[mf] = *(const bf16x8*)&hA[(mf * 16 + lr) * STRIDE + ks * 32 + lk * 8];
            #pragma unroll
            for (int nf = 0; nf < 4; ++nf)
                b[nf] = *(const bf16x8*)(gw2t + (size_t)(n0 + nf * 16 + lr) * 512 + ks * 32 + lk * 8);
            #pragma unroll
            for (int mf = 0; mf < 4; ++mf)
                #pragma unroll
                for (int nf = 0; nf < 4; ++nf)
                    acc[mf][nf] = MFMA(a[mf], b[nf], acc[mf][nf]);
        }
        #pragma unroll
        for (int nf = 0; nf < 4; ++nf) {
            int col = n0 + nf * 16 + lr;
            float bb = gb2[col];
            #pragma unroll
            for (int mf = 0; mf < 4; ++mf)
                #pragma unroll
                for (int j = 0; j < 4; ++j)
                    hB[(mf * 16 + lk * 4 + j) * STRIDE + col] = f2bf(elu_f(acc[mf][nf][j] + bb));
        }
    }
    __syncthreads();

    // L3: [64,512] @ gw3 [512,8] -> para, scalar (tiny)
    {
        const int row = t >> 3, e = t & 7;
        float acc = 0.f;
        for (int k = 0; k < 512; k += 8) {
            uint4 hv = *(const uint4*)&hB[row * STRIDE + k];
            acc += bf2f((ushort)(hv.x)) * gw3[(k + 0) * 8 + e];
            acc += bf2f((ushort)(hv.x >> 16)) * gw3[(k + 1) * 8 + e];
            acc += bf2f((ushort)(hv.y)) * gw3[(k + 2) * 8 + e];
            acc += bf2f((ushort)(hv.y >> 16)) * gw3[(k + 3) * 8 + e];
            acc += bf2f((ushort)(hv.z)) * gw3[(k + 4) * 8 + e];
            acc += bf2f((ushort)(hv.z >> 16)) * gw3[(k + 5) * 8 + e];
            acc += bf2f((ushort)(hv.w)) * gw3[(k + 6) * 8 + e];
            acc += bf2f((ushort)(hv.w >> 16)) * gw3[(k + 7) * 8 + e];
        }
        float p = elu_f(acc + gb3[e]);
        para[(size_t)(r0 + row) * 8 + e] = p;
        red[t] = p * p;
    }
    __syncthreads();
    for (int s = 256; s >= 1; s >>= 1) {
        if (t < s) red[t] += red[t + s];
        __syncthreads();
    }
    if (t == 0) partial[blockIdx.x] = red[0];
}

// ---------------- finalize: inv_norm ----------------
__global__ void finalize_kernel(const float* __restrict__ partial, float* __restrict__ invn) {
    __shared__ float red[256];
    const int t = threadIdx.x;
    red[t] = partial[t];
    __syncthreads();
    for (int s = 128; s >= 1; s >>= 1) {
        if (t < s) red[t] += red[t + s];
        __syncthreads();
    }
    if (t == 0) invn[0] = 1.0f / sqrtf(red[0]);
}

// ---------------- experts: 64 rows/block, loop 8 experts, MFMA all layers ----------------
__global__ __launch_bounds__(512, 2) void expert_kernel(
    const ushort* __restrict__ xz, const float* __restrict__ z,
    const ushort* __restrict__ W1t, const float* __restrict__ b1,
    const ushort* __restrict__ W2t, const float* __restrict__ b2,
    const ushort* __restrict__ W3t, const float* __restrict__ b3,
    const float* __restrict__ para, const float* __restrict__ invn,
    float* __restrict__ out)
{
    __shared__ ushort hA[64 * STRIDE];   // h1 | z (cols 512..543)
    __shared__ ushort hB[64 * STRIDE];   // x (cols 0..287) / h2 | z (cols 512..543)
    __shared__ float ps[64 * 8];
    const int t = threadIdx.x;
    const int lane = t & 63, w = t >> 6;
    const int lr = lane & 15, lk = lane >> 4;
    const int r0 = blockIdx.x * 64;

    // z cols (persist across experts: L1 writes cols<512 of hA, h2 writes cols<512 of hB,
    // x staging writes cols<288 of hB)
    for (int i = t; i < 2048; i += 512) {
        int r = i >> 5, c = i & 31;
        ushort v = f2bf(z[(size_t)(r0 + r) * 32 + c]);
        hA[r * STRIDE + 512 + c] = v;
        hB[r * STRIDE + 512 + c] = v;
    }
    ps[t] = para[(size_t)r0 * 8 + t];
    const float inv_norm = invn[0];

    float oacc[4][4];
    #pragma unroll
    for (int mf = 0; mf < 4; ++mf)
        #pragma unroll
        for (int j = 0; j < 4; ++j) oacc[mf][j] = 0.f;

    for (int e = 0; e < 8; ++e) {
        __syncthreads();   // prev expert L3 reads of hB done (and z/ps staging on e==0)
        for (int i = t; i < 64 * 36; i += 512) {   // stage x rows: 36 x (8 bf16) per row
            int r = i / 36, c = i % 36;
            *(uint4*)&hB[r * STRIDE + c * 8] = *(const uint4*)(xz + (size_t)(r0 + r) * 288 + c * 8);
        }
        __syncthreads();

        // ---- L1: x[64,288] @ W1t^T -> hA[64,512] ----
        {
            const ushort* Wt = W1t + (size_t)e * 512 * 288;
            f32x4 acc[4][4] = {};
            const int n0 = w * 64;
            for (int ks = 0; ks < 9; ++ks) {
                bf16x8 a[4], b[4];
                #pragma unroll
                for (int mf = 0; mf < 4; ++mf)
                    a[mf] = *(const bf16x8*)&hB[(mf * 16 + lr) * STRIDE + ks * 32 + lk * 8];
                #pragma unroll
                for (int nf = 0; nf < 4; ++nf)
                    b[nf] = *(const bf16x8*)(Wt + (size_t)(n0 + nf * 16 + lr) * 288 + ks * 32 + lk * 8);
                #pragma unroll
                for (int mf = 0; mf < 4; ++mf)
                    #pragma unroll
                    for (int nf = 0; nf < 4; ++nf)
                        acc[mf][nf] = MFMA(a[mf], b[nf], acc[mf][nf]);
            }
            #pragma unroll
            for (int nf = 0; nf < 4; ++nf) {
                int col = n0 + nf * 16 + lr;
                float bb = b1[e * 512 + col];
                #pragma unroll
                for (int mf = 0; mf < 4; ++mf)
                    #pragma unroll
                    for (int j = 0; j < 4; ++j)
                        hA[(mf * 16 + lk * 4 + j) * STRIDE + col] = f2bf(elu_f(acc[mf][nf][j] + bb));
            }
        }
        __syncthreads();

        // ---- L2: [h1|z][64,544] @ W2t^T -> hB[64,512] ----
        {
            const ushort* Wt = W2t + (size_t)e * 512 * 544;
            f32x4 acc[4][4] = {};
            const int n0 = w * 64;
            for (int ks = 0; ks < 17; ++ks) {
                bf16x8 a[4], b[4];
                #pragma unroll
                for (int mf = 0; mf < 4; ++mf)
                    a[mf] = *(const bf16x8*)&hA[(mf * 16 + lr) * STRIDE + ks * 32 + lk * 8];
                #pragma unroll
                for (int nf = 0; nf < 4; ++nf)
                    b[nf] = *(const bf16x8*)(Wt + (size_t)(n0 + nf * 16 + lr) * 544 + ks * 32 + lk * 8);
                #pragma unroll
                for (int mf = 0; mf < 4; ++mf)
                    #pragma unroll
                    for (int nf = 0; nf < 4; ++nf)
                        acc[mf][nf] = MFMA(a[mf], b[nf], acc[mf][nf]);
            }
            #pragma unroll
            for (int nf = 0; nf < 4; ++nf) {
                int col = n0 + nf * 16 + lr;
                float bb = b2[e * 512 + col];
                #pragma unroll
                for (int mf = 0; mf < 4; ++mf)
                    #pragma unroll
                    for (int j = 0; j < 4; ++j)
                        hB[(mf * 16 + lk * 4 + j) * STRIDE + col] = f2bf(elu_f(acc[mf][nf][j] + bb));
            }
        }
        __syncthreads();

        // ---- L3: [h2|z][64,544] @ W3t^T [128,544], gated accumulate ----
        {
            const ushort* Wt = W3t + (size_t)e * 128 * 544;
            f32x4 acc3[4] = {};
            const int n0 = w * 16;
            for (int ks = 0; ks < 17; ++ks) {
                bf16x8 b = *(const bf16x8*)(Wt + (size_t)(n0 + lr) * 544 + ks * 32 + lk * 8);
                #pragma unroll
                for (int mf = 0; mf < 4; ++mf) {
                    bf16x8 a = *(const bf16x8*)&hB[(mf * 16 + lr) * STRIDE + ks * 32 + lk * 8];
                    acc3[mf] = MFMA(a, b, acc3[mf]);
                }
            }
            float bb = b3[e * 128 + n0 + lr];
            #pragma unroll
            for (int mf = 0; mf < 4; ++mf)
                #pragma unroll
                for (int j = 0; j < 4; ++j) {
                    int row = mf * 16 + lk * 4 + j;
                    float h3 = elu_f(acc3[mf][j] + bb);
                    oacc[mf][j] += ps[row * 8 + e] * h3;
                }
        }
    }

    #pragma unroll
    for (int mf = 0; mf < 4; ++mf)
        #pragma unroll
        for (int j = 0; j < 4; ++j) {
            int row = mf * 16 + lk * 4 + j;
            float v = oacc[mf][j] * inv_norm;
            out[(size_t)(r0 + row) * 128 + w * 16 + lr] = 1.0f / (1.0f + __expf(-v));
        }
}

extern "C" void kernel_launch(void* const* d_in, const int* in_sizes, int n_in,
                              void* d_out, int out_size, void* d_ws, size_t ws_size,
                              hipStream_t stream) {
    const float* motions = (const float*)d_in[0];
    const float* z   = (const float*)d_in[1];
    const float* gw1 = (const float*)d_in[2];
    const float* gb1 = (const float*)d_in[3];
    const float* gw2 = (const float*)d_in[4];
    const float* gb2 = (const float*)d_in[5];
    const float* gw3 = (const float*)d_in[6];
    const float* gb3 = (const float*)d_in[7];
    const float* W1  = (const float*)d_in[8];
    const float* b1  = (const float*)d_in[9];
    const float* W2  = (const float*)d_in[10];
    const float* b2  = (const float*)d_in[11];
    const float* W3  = (const float*)d_in[12];
    const float* b3  = (const float*)d_in[13];
    float* out = (float*)d_out;

    char* W = (char*)d_ws;
    ushort* xz      = (ushort*)(W);              //  9,437,184 B
    ushort* gw1t    = (ushort*)(W + 9437184);    //    294,912
    ushort* gw2t    = (ushort*)(W + 9732096);    //    524,288
    ushort* W1t     = (ushort*)(W + 10256384);   //  2,359,296
    ushort* W2t     = (ushort*)(W + 12615680);   //  4,456,448
    ushort* W3t     = (ushort*)(W + 17072128);   //  1,114,112
    float*  para    = (float*) (W + 18186240);   //    524,288
    float*  partial = (float*) (W + 18710528);   //      1,024
    float*  invn    = (float*) (W + 18711552);   //          4

    prep_xz<<<dim3(4608), dim3(256), 0, stream>>>(motions, z, xz);
    prep_transpose<<<dim3(9, 16, 1), dim3(32, 8), 0, stream>>>(gw1, gw1t, 288, 512);
    prep_transpose<<<dim3(16, 16, 1), dim3(32, 8), 0, stream>>>(gw2, gw2t, 512, 512);
    prep_transpose<<<dim3(9, 16, 8), dim3(32, 8), 0, stream>>>(W1, W1t, 288, 512);
    prep_transpose<<<dim3(17, 16, 8), dim3(32, 8), 0, stream>>>(W2, W2t, 544, 512);
    prep_transpose<<<dim3(17, 4, 8), dim3(32, 8), 0, stream>>>(W3, W3t, 544, 128);

    gate_kernel<<<dim3(256), dim3(512), 0, stream>>>(xz, gw1t, gb1, gw2t, gb2, gw3, gb3,
                                                     para, partial);
    finalize_kernel<<<dim3(1), dim3(256), 0, stream>>>(partial, invn);
    expert_kernel<<<dim3(256), dim3(512), 0, stream>>>(xz, z, W1t, b1, W2t, b2, W3t, b3,
                                                       para, invn, out);
}